// Round 6
// baseline (418.607 us; speedup 1.0000x reference)
//
#include <hip/hip_runtime.h>

// fp8 blockwise-quantized GEMM for MI355X (gfx950) — round 9
//   y = (fp8(x/sx)*sx) @ (fp8(w)*sw)^T
// Round-8 post-mortem: GEMM stuck at MfmaUtil 34% (6300 cyc/kb-step vs MFMA
// demand 2208 = 64 x 34.5cyc): monolithic {reads -> MFMAs} phase serializes
// LDS/VALU/matrix pipes. Round-7's 4-phase port spilled (arch-VGPR capped at
// 128; premul + 6 pins + per-phase stage chains held too much live).
// Round-9 = the 4-phase fine interleave rebuilt SPILL-PROOF on the proven
// round-6 skeleton:
//  - top sync unchanged: STAGE 9 DMAs, counted vmcnt(9/8), s_barrier+fence.
//  - bottom sync unchanged: __syncthreads().
//  - body split into 4 quadrant phases (f-half x g-pair) with RAW s_barrier
//    between them (no fences needed: cur buffer is valid for the whole body;
//    mid barriers are pure alignment so LDS/matrix pipes mix across waves).
//  - operand reuse: P0(f0-3,g01) P1(f0-3,g23) P2(f4-7,g23) P3(f4-7,g01);
//    b2 reloaded 2x, a4/sx4 once per f-half -> 36 ds reads/wave/kb (vs 32).
//  - live set ~ b2(16)+a4(32)+sx4(16)+p(8): arch VGPR ~105 (r6 was 104).
//  - T5 setprio around each 8-MFMA cluster (phases create the role split).
// Spill tripwire: WRITE_SIZE must stay ~131 MB. Quant side unchanged (r8).

typedef int   v4i __attribute__((ext_vector_type(4)));
typedef int   v8i __attribute__((ext_vector_type(8)));
typedef float v4f __attribute__((ext_vector_type(4)));

constexpr int M  = 8192;
constexpr int K  = 4096;
constexpr int N  = 4096;
constexpr int KB = K / 128;  // 32
constexpr int NB = N / 128;  // 32

constexpr int XBLOCKS = (M / 16) * (KB / 2);                   // 8192
constexpr int WBLOCKS = (int)(((long long)N * K / 16) / 256);  // 4096

#define GLOBAL_AS __attribute__((address_space(1)))
#define LDS_AS    __attribute__((address_space(3)))

__device__ __forceinline__ void async16(const void* g, void* l) {
  // 16B/lane global->LDS DMA; LDS dest = wave-uniform base (+ lane*16 by HW)
  __builtin_amdgcn_global_load_lds((const GLOBAL_AS void*)g, (LDS_AS void*)l, 16, 0, 0);
}

// Fragment-order layout for quantized Q[R][K]:
//   group (rf = r>>4, kb = k>>7) at base (rf*KB + kb)*2048
//   k-chunk s (16 elems), row rr: byte (s&1)*1024 + ((s>>1)*16 + rr)*16
// matches the 16x16x128 f8f6f4 A/B operand layout (HW-validated rounds 1-8).

// ---------------- fused activation + weight quant (unchanged from r8) ----
__global__ __launch_bounds__(256) void quant_fused_kernel(
    const float* __restrict__ x, const float* __restrict__ w,
    unsigned char* __restrict__ xq, unsigned char* __restrict__ wq,
    float* __restrict__ xs_t /* [KB][M] */) {
  const int tid = threadIdx.x;
  if (blockIdx.x < XBLOCKS) {
    // ---- activation blockwise quant: wg = 16 rows x 2 kb (2 groups) ----
    const int gid2 = blockIdx.x;
    const int mf  = gid2 >> 4;        // 0..511 (row-block)
    const int kbp = gid2 & 15;        // 0..15  (kb pair)
    const int kb2 = tid >> 7;         // 0..1
    const int rr  = (tid >> 3) & 15;  // row within block
    const int s   = tid & 7;          // 16-elem k-chunk
    const int kb  = kbp * 2 + kb2;
    const int m   = mf * 16 + rr;

    const float4* px = (const float4*)(x + (long long)m * K + kb * 128 + s * 16);
    float4 v0 = px[0], v1 = px[1], v2 = px[2], v3 = px[3];

    float ax = 0.f;
#define AMAX4(v) ax = fmaxf(ax, fmaxf(fmaxf(fabsf(v.x), fabsf(v.y)), fmaxf(fabsf(v.z), fabsf(v.w))))
    AMAX4(v0); AMAX4(v1); AMAX4(v2); AMAX4(v3);
#undef AMAX4
#pragma unroll
    for (int d = 4; d >= 1; d >>= 1) ax = fmaxf(ax, __shfl_xor(ax, d, 8));
    const float scale = fmaxf(ax, 1e-12f) / 448.0f;  // matches reference RNE path

    int p0 = 0, p1 = 0, p2 = 0, p3 = 0;
    p0 = __builtin_amdgcn_cvt_pk_fp8_f32(v0.x / scale, v0.y / scale, p0, false);
    p0 = __builtin_amdgcn_cvt_pk_fp8_f32(v0.z / scale, v0.w / scale, p0, true);
    p1 = __builtin_amdgcn_cvt_pk_fp8_f32(v1.x / scale, v1.y / scale, p1, false);
    p1 = __builtin_amdgcn_cvt_pk_fp8_f32(v1.z / scale, v1.w / scale, p1, true);
    p2 = __builtin_amdgcn_cvt_pk_fp8_f32(v2.x / scale, v2.y / scale, p2, false);
    p2 = __builtin_amdgcn_cvt_pk_fp8_f32(v2.z / scale, v2.w / scale, p2, true);
    p3 = __builtin_amdgcn_cvt_pk_fp8_f32(v3.x / scale, v3.y / scale, p3, false);
    p3 = __builtin_amdgcn_cvt_pk_fp8_f32(v3.z / scale, v3.w / scale, p3, true);

    const int q = s >> 1, j = s & 1;
    *(v4i*)(xq + ((long long)(mf * KB + kb)) * 2048 + j * 1024 +
            (q * 16 + rr) * 16) = (v4i){p0, p1, p2, p3};

    if (s == 0) xs_t[(long long)kb * M + m] = scale;
  } else {
    // ---- weight fp8 cast (fragment-order output) ----
    const long long t = (long long)(blockIdx.x - XBLOCKS) * 256 + tid;  // N*K/16
    const int grp = (int)(t >> 7);
    const int idx = (int)(t & 127);
    const int l = idx >> 1, j = idx & 1;
    const int nf = grp >> 5, kb = grp & (KB - 1);
    const int n = nf * 16 + (l & 15);
    const int k = kb * 128 + (l >> 4) * 32 + j * 16;

    const float4* pw = (const float4*)(w + (long long)n * K + k);
    float4 v0 = pw[0], v1 = pw[1], v2 = pw[2], v3 = pw[3];
    int p0 = 0, p1 = 0, p2 = 0, p3 = 0;
    p0 = __builtin_amdgcn_cvt_pk_fp8_f32(v0.x, v0.y, p0, false);
    p0 = __builtin_amdgcn_cvt_pk_fp8_f32(v0.z, v0.w, p0, true);
    p1 = __builtin_amdgcn_cvt_pk_fp8_f32(v1.x, v1.y, p1, false);
    p1 = __builtin_amdgcn_cvt_pk_fp8_f32(v1.z, v1.w, p1, true);
    p2 = __builtin_amdgcn_cvt_pk_fp8_f32(v2.x, v2.y, p2, false);
    p2 = __builtin_amdgcn_cvt_pk_fp8_f32(v2.z, v2.w, p2, true);
    p3 = __builtin_amdgcn_cvt_pk_fp8_f32(v3.x, v3.y, p3, false);
    p3 = __builtin_amdgcn_cvt_pk_fp8_f32(v3.z, v3.w, p3, true);
    *(v4i*)(wq + (long long)grp * 2048 + j * 1024 + l * 16) = (v4i){p0, p1, p2, p3};
  }
}

// ---------------- 4-phase double-buffered fp8 GEMM, 256x256 tile ----------
// grid (N/256, M/256), 512 threads = 8 waves (wm 0..1 x wn 0..3); wave tile
// 128x64 = Fa8 x Fb4. Sync skeleton = round 6 (proven); body = 4 quadrant
// phases separated by raw s_barrier (alignment only, no correctness role).
__global__ __launch_bounds__(512, 2) void gemm_fp8_kernel(
    const unsigned char* __restrict__ xq, const unsigned char* __restrict__ wq,
    const float* __restrict__ xs_t /*[KB][M]*/,
    const float* __restrict__ wscale /*[NB][KB]*/,
    float* __restrict__ out) {
  __shared__ unsigned char Asm[2][16 * 2048];  // 64 KB
  __shared__ unsigned char Bsm[2][16 * 2048];  // 64 KB
  __shared__ float Ssm[2][256];                // 2 KB

  const int tid   = threadIdx.x;
  const int ntile = blockIdx.x;  // 0..15
  const int mtile = blockIdx.y;  // 0..31
  const int wave  = tid >> 6;    // 0..7
  const int lane  = tid & 63;
  const int wm = wave >> 2, wn = wave & 3;
  const int l15 = lane & 15, quad = lane >> 4;

  // wave-uniform w-scale per kb, broadcast via readlane (validated r6)
  const float wsv = wscale[(ntile * 2 + (wn >> 1)) * KB + (lane & 31)];

  const unsigned char* pa0 =
      xq + ((long long)(mtile * 16 + wave * 2) * KB) * 2048 + lane * 16;
  const unsigned char* pb0 =
      wq + ((long long)(ntile * 16 + wave * 2) * KB) * 2048 + lane * 16;
  const char* ps0 = (const char*)(xs_t + (long long)mtile * 256) + lane * 16;

  auto STAGE = [&](int nbuf, int kbi) {
    const long long koff = (long long)kbi * 2048;
#pragma unroll
    for (int t = 0; t < 4; ++t)  // A: group wave*2 + (t>>1), half t&1
      async16(pa0 + koff + (long long)(t >> 1) * (KB * 2048) + (t & 1) * 1024,
              &Asm[nbuf][(wave * 2 + (t >> 1)) * 2048 + (t & 1) * 1024]);
#pragma unroll
    for (int t = 0; t < 4; ++t)  // B: group wave*2 + (t>>1), half t&1
      async16(pb0 + koff + (long long)(t >> 1) * (KB * 2048) + (t & 1) * 1024,
              &Bsm[nbuf][(wave * 2 + (t >> 1)) * 2048 + (t & 1) * 1024]);
    // x-scale row (1KB): staged by wave 0 only (vmcnt is per-wave).
    if (wave == 0) async16(ps0 + (long long)kbi * (M * 4), &Ssm[nbuf][0]);
  };

  v4f acc[8][4];
#pragma unroll
  for (int f = 0; f < 8; ++f)
#pragma unroll
    for (int g = 0; g < 4; ++g) acc[f][g] = (v4f){0.f, 0.f, 0.f, 0.f};
  const v4f z = (v4f){0.f, 0.f, 0.f, 0.f};

  STAGE(0, 0);  // prologue prefetch

  v8i b2[2], a4[4];
  v4f sx4[4];

// load B frag-group (wn*4 + G) into b2[slot]
#define RD_B(slot, G)                                                          \
  {                                                                            \
    const unsigned char* pb_ = Bq + (wn * 4 + (G)) * 2048 + lane * 16;         \
    v4i lo_ = *(const v4i*)pb_;                                                \
    v4i hi_ = *(const v4i*)(pb_ + 1024);                                       \
    b2[slot][0] = lo_[0]; b2[slot][1] = lo_[1];                                \
    b2[slot][2] = lo_[2]; b2[slot][3] = lo_[3];                                \
    b2[slot][4] = hi_[0]; b2[slot][5] = hi_[1];                                \
    b2[slot][6] = hi_[2]; b2[slot][7] = hi_[3];                                \
  }
// load A frags FH*4..FH*4+3 and their scale rows
#define RD_A(FH)                                                               \
  _Pragma("unroll") for (int fl = 0; fl < 4; ++fl) {                           \
    const unsigned char* pa_ = Aq + (wm * 8 + (FH)*4 + fl) * 2048 + lane * 16; \
    v4i lo_ = *(const v4i*)pa_;                                                \
    v4i hi_ = *(const v4i*)(pa_ + 1024);                                       \
    a4[fl][0] = lo_[0]; a4[fl][1] = lo_[1];                                    \
    a4[fl][2] = lo_[2]; a4[fl][3] = lo_[3];                                    \
    a4[fl][4] = hi_[0]; a4[fl][5] = hi_[1];                                    \
    a4[fl][6] = hi_[2]; a4[fl][7] = hi_[3];                                    \
    sx4[fl] = *(const v4f*)&Ssm[cur][wm * 128 + ((FH)*4 + fl) * 16 + quad * 4];\
  }
// 8-MFMA quadrant cluster + exact f32 rescale (acc indices compile-time)
#define CLUSTER(FH, GP)                                                        \
  {                                                                            \
    asm volatile("s_waitcnt lgkmcnt(0)" ::: "memory");                         \
    __builtin_amdgcn_sched_barrier(0);                                         \
    __builtin_amdgcn_s_setprio(1);                                             \
    _Pragma("unroll") for (int fl = 0; fl < 4; ++fl) {                         \
      v4f p0_ = __builtin_amdgcn_mfma_scale_f32_16x16x128_f8f6f4(              \
          a4[fl], b2[0], z, 0, 0, 0, 0x7f7f7f7f, 0, 0x7f7f7f7f);               \
      v4f p1_ = __builtin_amdgcn_mfma_scale_f32_16x16x128_f8f6f4(              \
          a4[fl], b2[1], z, 0, 0, 0, 0x7f7f7f7f, 0, 0x7f7f7f7f);               \
      v4f s_ = sx4[fl] * ws;                                                   \
      acc[(FH)*4 + fl][(GP)*2]     += s_ * p0_;                                \
      acc[(FH)*4 + fl][(GP)*2 + 1] += s_ * p1_;                                \
    }                                                                          \
    __builtin_amdgcn_s_setprio(0);                                             \
  }

#pragma unroll 1
  for (int kb = 0; kb < KB; ++kb) {
    const int cur = kb & 1;
    if (kb < KB - 1) {
      STAGE(cur ^ 1, kb + 1);  // next-buffer batch; in flight over all phases
      if (wave == 0) asm volatile("s_waitcnt vmcnt(9)" ::: "memory");
      else           asm volatile("s_waitcnt vmcnt(8)" ::: "memory");
    } else {
      asm volatile("s_waitcnt vmcnt(0)" ::: "memory");
    }
    __builtin_amdgcn_s_barrier();  // cur-buffer DMAs retired on all waves
    asm volatile("" ::: "memory");
    __builtin_amdgcn_sched_barrier(0);

    const unsigned char* Aq = Asm[cur];
    const unsigned char* Bq = Bsm[cur];
    const float ws =
        __uint_as_float(__builtin_amdgcn_readlane(__float_as_uint(wsv), kb));

    // P0: (f0-3, g01)
    RD_B(0, 0); RD_B(1, 1);
    RD_A(0);
    CLUSTER(0, 0);
    __builtin_amdgcn_s_barrier();  // alignment only

    // P1: (f0-3, g23) — a4/sx4 reused
    RD_B(0, 2); RD_B(1, 3);
    CLUSTER(0, 1);
    __builtin_amdgcn_s_barrier();

    // P2: (f4-7, g23) — b2 reused
    RD_A(1);
    CLUSTER(1, 1);
    __builtin_amdgcn_s_barrier();

    // P3: (f4-7, g01) — a4/sx4 reused
    RD_B(0, 0); RD_B(1, 1);
    CLUSTER(1, 0);

    // bottom sync: drains reads of cur before next-iter DMAs may target it
    // (wave's kb+2 batch overwrites cur; issued only after this barrier).
    __syncthreads();
  }

  // ---- epilogue: C/D layout col = lane&15, row = quad*4 + reg ----
#pragma unroll
  for (int f = 0; f < 8; ++f) {
#pragma unroll
    for (int r = 0; r < 4; ++r) {
      const long long row = mtile * 256 + wm * 128 + f * 16 + quad * 4 + r;
      float* po = out + row * N + ntile * 256 + wn * 64 + l15;
#pragma unroll
      for (int g = 0; g < 4; ++g) po[g * 16] = acc[f][g][r];
    }
  }
}

extern "C" void kernel_launch(void* const* d_in, const int* in_sizes, int n_in,
                              void* d_out, int out_size, void* d_ws, size_t ws_size,
                              hipStream_t stream) {
  const float* x   = (const float*)d_in[0];  // [M,K]
  const float* w   = (const float*)d_in[1];  // [N,K]
  const float* wsc = (const float*)d_in[2];  // [NB,KB]
  float* out = (float*)d_out;                // [M,N] f32

  unsigned char* ws = (unsigned char*)d_ws;
  unsigned char* xq = ws;                                      // 32 MB frag-order
  unsigned char* wq = ws + (size_t)M * K;                      // 16 MB frag-order
  float* xs_t = (float*)(ws + (size_t)M * K + (size_t)N * K);  // 1 MB [KB][M]

  quant_fused_kernel<<<XBLOCKS + WBLOCKS, 256, 0, stream>>>(x, w, xq, wq, xs_t);
  gemm_fp8_kernel<<<dim3(N / 256, M / 256), 512, 0, stream>>>(xq, wq, xs_t, wsc, out);
}